// Round 19
// baseline (142.011 us; speedup 1.0000x reference)
//
#include <hip/hip_runtime.h>

#define NRES 384
#define NLIG 128
#define INC 384
#define OUTC 128
#define NTOT 512

// ---- bf16 ws regions (bf16-element offsets from ws base) ----
#define BT_RR   0            // [384][o*32+y]
#define BT_RL   1572864
#define BT_LR   3145728
#define BT_LL   4718592      // [512][o*32+y]
#define BF_RJ   6815744      // [384][32]
#define BF_LJ   6828032      // [4*128][32]
#define BF_LI   6844416      // [4*128][32]
// end 6860800 bf16 ~= 13.7 MB

#define WSTR2 34             // wb LDS row stride (bf16): 68B -> bank+17, coprime
#define FSTR  32             // fac LDS row stride
#define TSTR2 264            // out-tile LDS row stride

typedef __bf16 bf16x8 __attribute__((ext_vector_type(8)));
typedef __bf16 bf16x4 __attribute__((ext_vector_type(4)));
typedef float  f32x4  __attribute__((ext_vector_type(4)));

__device__ inline bf16x8 cvt8(const float* p) {
  f32x4 a = *(const f32x4*)p, b = *(const f32x4*)(p + 4);
  bf16x8 r;
  r[0] = (__bf16)a[0]; r[1] = (__bf16)a[1]; r[2] = (__bf16)a[2]; r[3] = (__bf16)a[3];
  r[4] = (__bf16)b[0]; r[5] = (__bf16)b[1]; r[6] = (__bf16)b[2]; r[7] = (__bf16)b[3];
  return r;
}

// --- kA: self-sufficient shattered stage: one (tt,nt,mt) tile per block ----
__global__ __launch_bounds__(256) void kA_make(
    const float* __restrict__ rec, const float* __restrict__ lig,
    const float* __restrict__ rl1w, const float* __restrict__ rl1b,
    const float* __restrict__ rl2w, const float* __restrict__ rl2b,
    const float* __restrict__ ll1w, const float* __restrict__ ll1b,
    const float* __restrict__ ll2w, const float* __restrict__ ll2b,
    const float* __restrict__ Wrr, const float* __restrict__ Wrl,
    const float* __restrict__ Wlr, const float* __restrict__ Wll,
    float* __restrict__ ws) {
  __shared__ __bf16 wb[256 * WSTR2];     // 17 KB
  __shared__ __bf16 fac[16 * FSTR];      // 1 KB
  __shared__ __bf16 tile[16 * TSTR2];    // 8.4 KB  -> ~26.4 KB total
  __bf16* B16 = (__bf16*)ws;
  int b = blockIdx.x, t = threadIdx.x;
  int l = t & 63, w = t >> 6;
  int lr16 = l & 15, lq = l >> 4;

  if (b < 1664) {
    int tt, local;
    if (b < 1152) { tt = b / 384; local = b % 384; }
    else          { tt = 3;       local = b - 1152; }
    int nt = local & 15, mt = local >> 4;
    const float *in, *w1, *b1, *W;
    __bf16* At;
    if (tt == 0)      { in = rec; w1 = rl1w; b1 = rl1b; W = Wrr; At = B16 + BT_RR; }
    else if (tt == 1) { in = rec; w1 = rl1w; b1 = rl1b; W = Wrl; At = B16 + BT_RL; }
    else if (tt == 2) { in = rec; w1 = rl2w; b1 = rl2b; W = Wlr; At = B16 + BT_LR; }
    else              { in = lig; w1 = ll1w; b1 = ll1b; W = Wll; At = B16 + BT_LL; }
    int n0 = nt * 256, m0 = mt * 16, o0 = nt * 8;

    // sub-phase 1: W[o0..o0+7][x*32+y] -> wb[oo*32+y][x]  (coalesced reads)
#pragma unroll
    for (int it = 0; it < 32; ++it) {
      int idx = it * 256 + t;            // 0..8191
      int oo = idx >> 10, r = idx & 1023, x = r >> 5, y = r & 31;
      wb[(oo * 32 + y) * WSTR2 + x] = (__bf16)W[(size_t)(o0 + oo) * 1024 + r];
    }
    // sub-phase 2: proj rows m0..m0+15, ch 0..31 via MFMA (kP's verified pattern)
#pragma unroll
    for (int ct = 0; ct < 2; ++ct) {
      int ch = ct * 16 + lr16;
      int arow = m0 + lr16;
      f32x4 acc = (f32x4){0.f, 0.f, 0.f, 0.f};
      for (int ks = 0; ks < 12; ++ks) {
        bf16x8 af = cvt8(in + (size_t)arow * INC + ks * 32 + lq * 8);
        bf16x8 bf = cvt8(w1 + (size_t)ch * INC + ks * 32 + lq * 8);
        acc = __builtin_amdgcn_mfma_f32_16x16x32_bf16(af, bf, acc, 0, 0, 0);
      }
      float bias = b1[ch];
      if (w == ct) {                     // one wave commits each ct (all compute)
#pragma unroll
        for (int e = 0; e < 4; ++e)
          fac[(4 * lq + e) * FSTR + ch] = (__bf16)(acc[e] + bias);
      }
    }
    __syncthreads();

    // sub-phase 3: At tile = wb(n x y) * fac(m x y)^T via MFMA
    int nw = w * 64;
    bf16x8 wv[4];
#pragma unroll
    for (int q = 0; q < 4; ++q)
      wv[q] = *(const bf16x8*)&wb[(nw + q * 16 + lr16) * WSTR2 + lq * 8];
    bf16x8 fv = *(const bf16x8*)&fac[lr16 * FSTR + lq * 8];
    f32x4 acc[4];
#pragma unroll
    for (int q = 0; q < 4; ++q) acc[q] = (f32x4){0.f, 0.f, 0.f, 0.f};
#pragma unroll
    for (int q = 0; q < 4; ++q)          // D-row = n (wv), D-col = m (fv)
      acc[q] = __builtin_amdgcn_mfma_f32_16x16x32_bf16(wv[q], fv, acc[q], 0, 0, 0);
#pragma unroll
    for (int q = 0; q < 4; ++q) {
      bf16x4 v;
#pragma unroll
      for (int e = 0; e < 4; ++e) v[e] = (__bf16)acc[q][e];
      *(bf16x4*)&tile[lr16 * TSTR2 + nw + q * 16 + 4 * lq] = v;
    }
    __syncthreads();
    // dense copy-out: 512B-contiguous run per m-row
    for (int idx = t; idx < 512; idx += 256) {
      int m = idx >> 5, nl = (idx & 31) * 8;
      bf16x8 v = *(const bf16x8*)&tile[m * TSTR2 + nl];
      *(bf16x8*)(At + (size_t)(m0 + m) * 4096 + n0 + nl) = v;
    }
  } else {                               // table blocks: bf16 factor tables
    int tb = b - 1664;
    const float *in, *wsrc, *bsrc;
    __bf16* outb;
    int rows, row0;
    if (tb < 2)      { in = rec; wsrc = rl2w; bsrc = rl2b; outb = B16 + BF_RJ; rows = 192; row0 = tb * 192; }
    else if (tb < 4) { in = lig; wsrc = ll2w; bsrc = ll2b; outb = B16 + BF_LJ; rows = 256; row0 = (tb - 2) * 256; }
    else             { in = lig; wsrc = ll1w; bsrc = ll1b; outb = B16 + BF_LI; rows = 256; row0 = (tb - 4) * 256; }
    int rtiles = rows >> 4;
    int tpw = (rtiles * 2) >> 2;         // 6 or 8 tiles per wave
    for (int ti = 0; ti < tpw; ++ti) {
      int tile_ = w * tpw + ti;
      int rt = tile_ >> 1, ct = tile_ & 1;
      int ch = ct * 16 + lr16;
      int arow = row0 + rt * 16 + lr16;
      f32x4 acc = (f32x4){0.f, 0.f, 0.f, 0.f};
      for (int ks = 0; ks < 12; ++ks) {
        bf16x8 af = cvt8(in + (size_t)arow * INC + ks * 32 + lq * 8);
        bf16x8 bf = cvt8(wsrc + (size_t)ch * INC + ks * 32 + lq * 8);
        acc = __builtin_amdgcn_mfma_f32_16x16x32_bf16(af, bf, acc, 0, 0, 0);
      }
      float bias = bsrc[ch];
#pragma unroll
      for (int e = 0; e < 4; ++e)
        outb[(size_t)(row0 + rt * 16 + 4 * lq + e) * 32 + ch] = (__bf16)(acc[e] + bias);
    }
  }
}

// --- k3: four quadrants via MFMA; rl/lr average their factor in-register ---
__global__ __launch_bounds__(256) void k3_mfma(
    const float* __restrict__ ws, float* __restrict__ out,
    const float* __restrict__ rrb, const float* __restrict__ rlb,
    const float* __restrict__ lrb, const float* __restrict__ llb) {
  const __bf16* B16 = (const __bf16*)ws;
  int b = blockIdx.x, t = threadIdx.x;
  int l = t & 63, w = t >> 6;
  int lr16 = l & 15, lq = l >> 4;

  if (b < 1920) {                  // rr / rl / lr  (K = 32, one mfma per tile)
    const __bf16* At;
    const float* bias;
    float* outp;
    size_t jstr;
    bf16x8 fj[2];
    if (b < 1152) {                // rr: fc = BF_RJ directly
      int i = b / 3, jt = b - 3 * i;
      At = B16 + BT_RR + (size_t)i * 4096;
      const __bf16* fc = B16 + BF_RJ + jt * 4096;
#pragma unroll
      for (int jj = 0; jj < 2; ++jj)
        fj[jj] = *(const bf16x8*)(fc + (size_t)(w * 32 + jj * 16 + lr16) * 32 + lq * 8);
      bias = rrb; outp = out + ((size_t)i * NTOT + jt * 128) * OUTC; jstr = OUTC;
    } else if (b < 1536) {         // rl: fc = mean_m BF_LJ
      int i = b - 1152;
      At = B16 + BT_RL + (size_t)i * 4096;
      const __bf16* lj = B16 + BF_LJ;
#pragma unroll
      for (int jj = 0; jj < 2; ++jj) {
        size_t off = (size_t)(w * 32 + jj * 16 + lr16) * 32 + lq * 8;
        float s[8] = {0, 0, 0, 0, 0, 0, 0, 0};
#pragma unroll
        for (int mm = 0; mm < 4; ++mm) {
          bf16x8 v = *(const bf16x8*)(lj + mm * 4096 + off);
#pragma unroll
          for (int e = 0; e < 8; ++e) s[e] += (float)v[e];
        }
#pragma unroll
        for (int e = 0; e < 8; ++e) fj[jj][e] = (__bf16)(0.25f * s[e]);
      }
      bias = rlb; outp = out + ((size_t)i * NTOT + NRES) * OUTC; jstr = OUTC;
    } else {                       // lr: fc = mean_m BF_LI (transposed output)
      int i = b - 1536;
      At = B16 + BT_LR + (size_t)i * 4096;
      const __bf16* li = B16 + BF_LI;
#pragma unroll
      for (int jj = 0; jj < 2; ++jj) {
        size_t off = (size_t)(w * 32 + jj * 16 + lr16) * 32 + lq * 8;
        float s[8] = {0, 0, 0, 0, 0, 0, 0, 0};
#pragma unroll
        for (int mm = 0; mm < 4; ++mm) {
          bf16x8 v = *(const bf16x8*)(li + mm * 4096 + off);
#pragma unroll
          for (int e = 0; e < 8; ++e) s[e] += (float)v[e];
        }
#pragma unroll
        for (int e = 0; e < 8; ++e) fj[jj][e] = (__bf16)(0.25f * s[e]);
      }
      bias = lrb; outp = out + (size_t)NRES * NTOT * OUTC + (size_t)i * OUTC;
      jstr = (size_t)NTOT * OUTC;
    }
    f32x4 acc[2][8];
#pragma unroll
    for (int jj = 0; jj < 2; ++jj)
#pragma unroll
      for (int ot = 0; ot < 8; ++ot) acc[jj][ot] = (f32x4){0.f, 0.f, 0.f, 0.f};
#pragma unroll
    for (int oc = 0; oc < 2; ++oc) {
      bf16x8 av[4];
#pragma unroll
      for (int o4 = 0; o4 < 4; ++o4)
        av[o4] = *(const bf16x8*)(At + (size_t)((oc * 4 + o4) * 16 + lr16) * 32 + lq * 8);
#pragma unroll
      for (int jj = 0; jj < 2; ++jj)
#pragma unroll
        for (int o4 = 0; o4 < 4; ++o4)   // D-row = o, D-col = j
          acc[jj][oc * 4 + o4] =
              __builtin_amdgcn_mfma_f32_16x16x32_bf16(av[o4], fj[jj], acc[jj][oc * 4 + o4], 0, 0, 0);
    }
#pragma unroll
    for (int jj = 0; jj < 2; ++jj) {
      int j = w * 32 + jj * 16 + lr16;
#pragma unroll
      for (int ot = 0; ot < 8; ++ot) {
        f32x4 b4 = *(const f32x4*)&bias[ot * 16 + 4 * lq];
        f32x4 v = acc[jj][ot] + b4;
        *(f32x4*)&outp[(size_t)j * jstr + ot * 16 + 4 * lq] = v;
      }
    }
  } else {                         // ll: K = 128 (4 m-slices of 32)
    int il = b - 1920;
    f32x4 acc[2][8];
#pragma unroll
    for (int jj = 0; jj < 2; ++jj)
#pragma unroll
      for (int ot = 0; ot < 8; ++ot) acc[jj][ot] = (f32x4){0.f, 0.f, 0.f, 0.f};
    for (int m = 0; m < 4; ++m) {
      const __bf16* At = B16 + BT_LL + (size_t)(m * 128 + il) * 4096;
      const __bf16* fc = B16 + BF_LJ + m * 4096;
      bf16x8 fj[2];
#pragma unroll
      for (int jj = 0; jj < 2; ++jj)
        fj[jj] = *(const bf16x8*)(fc + (size_t)(w * 32 + jj * 16 + lr16) * 32 + lq * 8);
#pragma unroll
      for (int oc = 0; oc < 2; ++oc) {
        bf16x8 av[4];
#pragma unroll
        for (int o4 = 0; o4 < 4; ++o4)
          av[o4] = *(const bf16x8*)(At + (size_t)((oc * 4 + o4) * 16 + lr16) * 32 + lq * 8);
#pragma unroll
        for (int jj = 0; jj < 2; ++jj)
#pragma unroll
          for (int o4 = 0; o4 < 4; ++o4)
            acc[jj][oc * 4 + o4] =
                __builtin_amdgcn_mfma_f32_16x16x32_bf16(av[o4], fj[jj], acc[jj][oc * 4 + o4], 0, 0, 0);
      }
    }
    float* outp = out + ((size_t)(NRES + il) * NTOT + NRES) * OUTC;
#pragma unroll
    for (int jj = 0; jj < 2; ++jj) {
      int j = w * 32 + jj * 16 + lr16;
#pragma unroll
      for (int ot = 0; ot < 8; ++ot) {
        f32x4 b4 = *(const f32x4*)&llb[ot * 16 + 4 * lq];
        f32x4 v = 0.25f * acc[jj][ot] + b4;
        *(f32x4*)&outp[(size_t)j * OUTC + ot * 16 + 4 * lq] = v;
      }
    }
  }
}

extern "C" void kernel_launch(void* const* d_in, const int* in_sizes, int n_in,
                              void* d_out, int out_size, void* d_ws, size_t ws_size,
                              hipStream_t stream) {
  const float* rec  = (const float*)d_in[0];
  const float* lig  = (const float*)d_in[1];
  const float* rl1w = (const float*)d_in[3];
  const float* rl1b = (const float*)d_in[4];
  const float* rl2w = (const float*)d_in[5];
  const float* rl2b = (const float*)d_in[6];
  const float* ll1w = (const float*)d_in[7];
  const float* ll1b = (const float*)d_in[8];
  const float* ll2w = (const float*)d_in[9];
  const float* ll2b = (const float*)d_in[10];
  const float* rrw  = (const float*)d_in[11];
  const float* rrb  = (const float*)d_in[12];
  const float* rlw  = (const float*)d_in[13];
  const float* rlb  = (const float*)d_in[14];
  const float* lrw  = (const float*)d_in[15];
  const float* lrb  = (const float*)d_in[16];
  const float* llw  = (const float*)d_in[17];
  const float* llb  = (const float*)d_in[18];
  float* out = (float*)d_out;
  float* ws  = (float*)d_ws;

  hipLaunchKernelGGL(kA_make, dim3(1670), dim3(256), 0, stream,
                     rec, lig, rl1w, rl1b, rl2w, rl2b, ll1w, ll1b, ll2w, ll2b,
                     rrw, rlw, lrw, llw, ws);
  hipLaunchKernelGGL(k3_mfma, dim3(2048), dim3(256), 0, stream,
                     ws, out, rrb, rlb, lrb, llb);
}

// Round 21
// 50.684 us; speedup vs baseline: 2.8019x; 2.8019x over previous
//
#include <hip/hip_runtime.h>

#define NRES 384
#define NLIG 128
#define INC 384
#define OUTC 128
#define NTOT 512

// ---- f32 ws regions (float offsets) ----
#define WS_RI   0           // [384][32]
#define WS_RJ   12288       // [384][32]
#define WS_LI   24576       // [512][32]  (m*128+nl)
#define WS_LJ   40960       // [512][32]
#define WS_BF16 57344       // bf16 area starts here (float offset)

// ---- bf16 regions (bf16-element offsets from WS_BF16) ----
#define BT_RR   0            // [384][o*32+y]
#define BT_RL   1572864
#define BT_LR   3145728
#define BT_LL   4718592      // [512][o*32+y]
#define BF_RJ   6815744      // [384][32]
#define BF_LJM  6828032      // [128][32]  mean_m l_j
#define BF_LIM  6832128      // [128][32]  mean_m l_i
#define BF_LJ   6836224      // [4*128][32]
#define BF_RI   6852608      // [384][32]
#define BF_LI   6864896      // [512][32]
#define BW_W    6881280      // 4 x [n=o*32+y][x] bf16
// end 7405568 bf16 -> total ws ~15.0 MB

typedef __bf16 bf16x8 __attribute__((ext_vector_type(8)));
typedef __bf16 bf16x4 __attribute__((ext_vector_type(4)));
typedef float  f32x4  __attribute__((ext_vector_type(4)));

__device__ inline bf16x8 cvt8(const float* p) {
  f32x4 a = *(const f32x4*)p, b = *(const f32x4*)(p + 4);
  bf16x8 r;
  r[0] = (__bf16)a[0]; r[1] = (__bf16)a[1]; r[2] = (__bf16)a[2]; r[3] = (__bf16)a[3];
  r[4] = (__bf16)b[0]; r[5] = (__bf16)b[1]; r[6] = (__bf16)b[2]; r[7] = (__bf16)b[3];
  return r;
}

// --- kP: projections (blocks 0..27) + W relayout, 1 o-row/block (28..539) --
__global__ __launch_bounds__(256) void kP_proj(
    const float* __restrict__ rec, const float* __restrict__ lig,
    const float* __restrict__ rl1w, const float* __restrict__ rl1b,
    const float* __restrict__ rl2w, const float* __restrict__ rl2b,
    const float* __restrict__ ll1w, const float* __restrict__ ll1b,
    const float* __restrict__ ll2w, const float* __restrict__ ll2b,
    const float* __restrict__ Wrr, const float* __restrict__ Wrl,
    const float* __restrict__ Wlr, const float* __restrict__ Wll,
    float* __restrict__ ws) {
  __shared__ float lds[32 * 33];
  int b = blockIdx.x, t = threadIdx.x;
  __bf16* B16 = (__bf16*)(ws + WS_BF16);
  if (b >= 28) {                   // W relayout: Wb[n=o*32+y][x] bf16
    int bb = b - 28;               // 0..511
    int tt = bb >> 7, o = bb & 127;
    const float* W = tt == 0 ? Wrr : tt == 1 ? Wrl : tt == 2 ? Wlr : Wll;
    __bf16* Wb = B16 + BW_W + tt * 131072;
#pragma unroll
    for (int k = 0; k < 4; ++k) {
      int idx = k * 256 + t;       // 0..1023 = x*32+y
      int x = idx >> 5, y = idx & 31;
      lds[y * 33 + x] = W[(size_t)o * 1024 + idx];
    }
    __syncthreads();
#pragma unroll
    for (int k = 0; k < 4; ++k) {
      int idx = k * 256 + t;       // 0..1023 = y*32+x
      int y = idx >> 5, x = idx & 31;
      Wb[(size_t)(o * 32 + y) * 32 + x] = (__bf16)lds[y * 33 + x];
    }
    return;
  }
  int l = t & 63, w = t >> 6;
  int lr16 = l & 15, lq = l >> 4;
  int pair = w >> 1, rh = w & 1;

  const float* in;
  const float *w1, *b1, *w2, *b2;
  float *o1, *o2;
  __bf16 *bf1, *bf2;
  int row0;
  if (b < 12) {
    row0 = b * 32;
    in = rec; w1 = rl1w; b1 = rl1b; w2 = rl2w; b2 = rl2b;
    o1 = ws + WS_RI; o2 = ws + WS_RJ;
    bf1 = B16 + BF_RI; bf2 = B16 + BF_RJ;
  } else {
    row0 = (b - 12) * 32;
    in = lig; w1 = ll1w; b1 = ll1b; w2 = ll2w; b2 = ll2b;
    o1 = ws + WS_LI; o2 = ws + WS_LJ;
    bf1 = B16 + BF_LI; bf2 = B16 + BF_LJ;
  }
  const float* wsrc = pair ? w2 : w1;
  const float* bsrc = pair ? b2 : b1;
  float* osrc = pair ? o2 : o1;
  __bf16* bdst = pair ? bf2 : bf1;
  int arow = row0 + rh * 16 + lr16;

  f32x4 acc[2];
#pragma unroll
  for (int ci = 0; ci < 2; ++ci) acc[ci] = (f32x4){0.f, 0.f, 0.f, 0.f};
  for (int ks = 0; ks < 12; ++ks) {
    bf16x8 af = cvt8(in + (size_t)arow * INC + ks * 32 + lq * 8);
#pragma unroll
    for (int ci = 0; ci < 2; ++ci) {
      int ch = ci * 16 + lr16;
      bf16x8 bf = cvt8(wsrc + (size_t)ch * INC + ks * 32 + lq * 8);
      acc[ci] = __builtin_amdgcn_mfma_f32_16x16x32_bf16(af, bf, acc[ci], 0, 0, 0);
    }
  }
#pragma unroll
  for (int ci = 0; ci < 2; ++ci) {
    int c = ci * 16 + lr16;
    float bias = bsrc[c];
#pragma unroll
    for (int e = 0; e < 4; ++e) {
      int r = row0 + rh * 16 + 4 * lq + e;
      float v = acc[ci][e] + bias;
      osrc[r * 32 + c] = v;
      bdst[r * 32 + c] = (__bf16)v;
    }
  }
}

// --- k2: At = facB @ Wb^T via MFMA; LDS-staged tile -> dense 512B-run stores
#define TSTR 264   // bf16 row stride: 528B, 16B-aligned rows
__global__ __launch_bounds__(256) void k2_makeA(float* __restrict__ ws) {
  __shared__ __bf16 tile[128 * TSTR];    // 66 KB
  int b = blockIdx.x, t = threadIdx.x;
  __bf16* B16 = (__bf16*)(ws + WS_BF16);
  if (b >= 256) {                  // means: ljm/lim bf16 [128][32]
    const float* lj = ws + WS_LJ;
    const float* li = ws + WS_LI;
    __bf16* dm = B16 + BF_LJM;
    __bf16* di = B16 + BF_LIM;
    for (int k = 0; k < 16; ++k) {
      int idx = k * 256 + t;
      dm[idx] = (__bf16)(0.25f * (lj[idx] + lj[4096 + idx] + lj[8192 + idx] + lj[12288 + idx]));
      di[idx] = (__bf16)(0.25f * (li[idx] + li[4096 + idx] + li[8192 + idx] + li[12288 + idx]));
    }
    return;
  }
  int tt = b >> 6, sub = b & 63;
  int nt = sub >> 2, mq = sub & 3;
  const __bf16* facB;
  __bf16* At;
  int M;
  if (tt == 0)      { facB = B16 + BF_RI; At = B16 + BT_RR; M = 384; }
  else if (tt == 1) { facB = B16 + BF_RI; At = B16 + BT_RL; M = 384; }
  else if (tt == 2) { facB = B16 + BF_RJ; At = B16 + BT_LR; M = 384; }
  else              { facB = B16 + BF_LI; At = B16 + BT_LL; M = 512; }
  const __bf16* Wb = B16 + BW_W + tt * 131072;
  int l = t & 63, w = t >> 6;
  int lr16 = l & 15, lq = l >> 4;
  int nw = w * 64;                 // local n base for this wave
  int n0w = nt * 256 + nw;         // global n base
  int mspan = M >> 2;              // 96 or 128
  int mtiles = M >> 6;             // mspan/16
  int m0 = mq * mspan;

  bf16x8 wv[4];
#pragma unroll
  for (int q = 0; q < 4; ++q)
    wv[q] = *(const bf16x8*)(Wb + (size_t)(n0w + q * 16 + lr16) * 32 + lq * 8);

  for (int mt = 0; mt < mtiles; ++mt) {
    bf16x8 fv = *(const bf16x8*)(facB + (size_t)(m0 + mt * 16 + lr16) * 32 + lq * 8);
    f32x4 acc[4];
#pragma unroll
    for (int q = 0; q < 4; ++q) acc[q] = (f32x4){0.f, 0.f, 0.f, 0.f};
#pragma unroll
    for (int q = 0; q < 4; ++q)    // D-row = n, D-col = m
      acc[q] = __builtin_amdgcn_mfma_f32_16x16x32_bf16(wv[q], fv, acc[q], 0, 0, 0);
    int ml = mt * 16 + lr16;       // local m row
#pragma unroll
    for (int q = 0; q < 4; ++q) {
      bf16x4 v;
#pragma unroll
      for (int e = 0; e < 4; ++e) v[e] = (__bf16)acc[q][e];
      *(bf16x4*)&tile[ml * TSTR + nw + q * 16 + 4 * lq] = v;
    }
  }
  __syncthreads();
  // dense copy-out: 512B-contiguous run per row, rows 8KB apart
  int total8 = mspan * 32;         // 8-bf16 units (row = 32 units of 16B)
  for (int idx = t; idx < total8; idx += 256) {
    int m = idx >> 5, nl = (idx & 31) * 8;
    bf16x8 v = *(const bf16x8*)&tile[m * TSTR + nl];
    *(bf16x8*)(At + (size_t)(m0 + m) * 4096 + nt * 256 + nl) = v;
  }
}

// --- k3: four quadrants via MFMA; D-rows = o so stores are float4 ----------
__global__ __launch_bounds__(256) void k3_mfma(
    const float* __restrict__ ws, float* __restrict__ out,
    const float* __restrict__ rrb, const float* __restrict__ rlb,
    const float* __restrict__ lrb, const float* __restrict__ llb) {
  const __bf16* B16 = (const __bf16*)(ws + WS_BF16);
  int b = blockIdx.x, t = threadIdx.x;
  int l = t & 63, w = t >> 6;
  int lr16 = l & 15, lq = l >> 4;

  if (b < 1920) {                  // rr / rl / lr  (K = 32, one mfma per tile)
    const __bf16* At;
    const __bf16* fc;
    const float* bias;
    float* outp;
    size_t jstr;
    if (b < 1152) {                // rr
      int i = b / 3, jt = b - 3 * i;
      At = B16 + BT_RR + (size_t)i * 4096;
      fc = B16 + BF_RJ + jt * 4096;
      bias = rrb; outp = out + ((size_t)i * NTOT + jt * 128) * OUTC; jstr = OUTC;
    } else if (b < 1536) {         // rl
      int i = b - 1152;
      At = B16 + BT_RL + (size_t)i * 4096;
      fc = B16 + BF_LJM;
      bias = rlb; outp = out + ((size_t)i * NTOT + NRES) * OUTC; jstr = OUTC;
    } else {                       // lr (transposed output)
      int i = b - 1536;
      At = B16 + BT_LR + (size_t)i * 4096;
      fc = B16 + BF_LIM;
      bias = lrb; outp = out + (size_t)NRES * NTOT * OUTC + (size_t)i * OUTC;
      jstr = (size_t)NTOT * OUTC;
    }
    bf16x8 fj[2];
#pragma unroll
    for (int jj = 0; jj < 2; ++jj)
      fj[jj] = *(const bf16x8*)(fc + (size_t)(w * 32 + jj * 16 + lr16) * 32 + lq * 8);
    f32x4 acc[2][8];
#pragma unroll
    for (int jj = 0; jj < 2; ++jj)
#pragma unroll
      for (int ot = 0; ot < 8; ++ot) acc[jj][ot] = (f32x4){0.f, 0.f, 0.f, 0.f};
#pragma unroll
    for (int oc = 0; oc < 2; ++oc) {
      bf16x8 av[4];
#pragma unroll
      for (int o4 = 0; o4 < 4; ++o4)
        av[o4] = *(const bf16x8*)(At + (size_t)((oc * 4 + o4) * 16 + lr16) * 32 + lq * 8);
#pragma unroll
      for (int jj = 0; jj < 2; ++jj)
#pragma unroll
        for (int o4 = 0; o4 < 4; ++o4)   // D-row = o, D-col = j
          acc[jj][oc * 4 + o4] =
              __builtin_amdgcn_mfma_f32_16x16x32_bf16(av[o4], fj[jj], acc[jj][oc * 4 + o4], 0, 0, 0);
    }
#pragma unroll
    for (int jj = 0; jj < 2; ++jj) {
      int j = w * 32 + jj * 16 + lr16;
#pragma unroll
      for (int ot = 0; ot < 8; ++ot) {
        f32x4 b4 = *(const f32x4*)&bias[ot * 16 + 4 * lq];
        f32x4 v = acc[jj][ot] + b4;
        *(f32x4*)&outp[(size_t)j * jstr + ot * 16 + 4 * lq] = v;
      }
    }
  } else {                         // ll: K = 128 (4 m-slices of 32)
    int il = b - 1920;
    f32x4 acc[2][8];
#pragma unroll
    for (int jj = 0; jj < 2; ++jj)
#pragma unroll
      for (int ot = 0; ot < 8; ++ot) acc[jj][ot] = (f32x4){0.f, 0.f, 0.f, 0.f};
    for (int m = 0; m < 4; ++m) {
      const __bf16* At = B16 + BT_LL + (size_t)(m * 128 + il) * 4096;
      const __bf16* fc = B16 + BF_LJ + m * 4096;
      bf16x8 fj[2];
#pragma unroll
      for (int jj = 0; jj < 2; ++jj)
        fj[jj] = *(const bf16x8*)(fc + (size_t)(w * 32 + jj * 16 + lr16) * 32 + lq * 8);
#pragma unroll
      for (int oc = 0; oc < 2; ++oc) {
        bf16x8 av[4];
#pragma unroll
        for (int o4 = 0; o4 < 4; ++o4)
          av[o4] = *(const bf16x8*)(At + (size_t)((oc * 4 + o4) * 16 + lr16) * 32 + lq * 8);
#pragma unroll
        for (int jj = 0; jj < 2; ++jj)
#pragma unroll
          for (int o4 = 0; o4 < 4; ++o4)
            acc[jj][oc * 4 + o4] =
                __builtin_amdgcn_mfma_f32_16x16x32_bf16(av[o4], fj[jj], acc[jj][oc * 4 + o4], 0, 0, 0);
      }
    }
    float* outp = out + ((size_t)(NRES + il) * NTOT + NRES) * OUTC;
#pragma unroll
    for (int jj = 0; jj < 2; ++jj) {
      int j = w * 32 + jj * 16 + lr16;
#pragma unroll
      for (int ot = 0; ot < 8; ++ot) {
        f32x4 b4 = *(const f32x4*)&llb[ot * 16 + 4 * lq];
        f32x4 v = 0.25f * acc[jj][ot] + b4;
        *(f32x4*)&outp[(size_t)j * OUTC + ot * 16 + 4 * lq] = v;
      }
    }
  }
}

extern "C" void kernel_launch(void* const* d_in, const int* in_sizes, int n_in,
                              void* d_out, int out_size, void* d_ws, size_t ws_size,
                              hipStream_t stream) {
  const float* rec  = (const float*)d_in[0];
  const float* lig  = (const float*)d_in[1];
  const float* rl1w = (const float*)d_in[3];
  const float* rl1b = (const float*)d_in[4];
  const float* rl2w = (const float*)d_in[5];
  const float* rl2b = (const float*)d_in[6];
  const float* ll1w = (const float*)d_in[7];
  const float* ll1b = (const float*)d_in[8];
  const float* ll2w = (const float*)d_in[9];
  const float* ll2b = (const float*)d_in[10];
  const float* rrw  = (const float*)d_in[11];
  const float* rrb  = (const float*)d_in[12];
  const float* rlw  = (const float*)d_in[13];
  const float* rlb  = (const float*)d_in[14];
  const float* lrw  = (const float*)d_in[15];
  const float* lrb  = (const float*)d_in[16];
  const float* llw  = (const float*)d_in[17];
  const float* llb  = (const float*)d_in[18];
  float* out = (float*)d_out;
  float* ws  = (float*)d_ws;

  hipLaunchKernelGGL(kP_proj, dim3(540), dim3(256), 0, stream,
                     rec, lig, rl1w, rl1b, rl2w, rl2b, ll1w, ll1b, ll2w, ll2b,
                     rrw, rlw, lrw, llw, ws);
  hipLaunchKernelGGL(k2_makeA, dim3(257), dim3(256), 0, stream, ws);
  hipLaunchKernelGGL(k3_mfma, dim3(2048), dim3(256), 0, stream,
                     ws, out, rrb, rlb, lrb, llb);
}